// Round 6
// baseline (173.668 us; speedup 1.0000x reference)
//
#include <hip/hip_runtime.h>

// DynamicMaskHead fused v5b (MI355X / gfx950)
// pack_kernel: (mask_shift, mask_feats) -> rec (4,16384,12) records:
//   {m0, m1, f0..f7, pad, pad} -> per-pixel input = 3 x global_load_dwordx4.
// dmh_kernel: grid = n_inst x 8 row-groups (16 logits rows -> 32 out rows).
//   17x128 logits tile (clamped halo row above) via 10->8->8->1 MLP with
//   block-uniform scalar weights, parity-split LDS, factor-2 aligned_bilinear
//   closed form, NON-TEMPORAL float4 stores (keep L2 for rec re-reads).
//
// aligned_bilinear(factor=2): uy=max(Y-1,0); odd Y -> copy logits row
// (Y-1)/2; even Y -> avg rows (Y/2-1, Y/2); Y=0 falls out via clamped halo.
// In X: out[4l..4l+3] from logits cols {2l-1, 2l, 2l+1}.

#define HW 16384
#define NP 169
#define RECW 12   // floats per record

typedef float nf4 __attribute__((ext_vector_type(4)));  // NT-store-compatible

__global__ __launch_bounds__(256)
void pack_kernel(const float* __restrict__ mf, const float* __restrict__ msf,
                 float* __restrict__ rec)
{
    const int g   = blockIdx.x * 256 + threadIdx.x;   // 0..65535
    const int img = g >> 14;
    const int p   = g & 16383;
    const float* fb = mf + (size_t)img * 8 * HW + p;
    const float2 ms = *(const float2*)(msf + 2 * p);
    float4* o = (float4*)(rec + (size_t)g * RECW);
    o[0] = make_float4(ms.x, ms.y, fb[0], fb[HW]);
    o[1] = make_float4(fb[2 * HW], fb[3 * HW], fb[4 * HW], fb[5 * HW]);
    o[2] = make_float4(fb[6 * HW], fb[7 * HW], 0.f, 0.f);
}

__global__ __launch_bounds__(256, 6)
void dmh_kernel(const float* __restrict__ shifts,       // (n,2)
                const float* __restrict__ inst_params,  // (n,169)
                const int*   __restrict__ im_inds,      // (n,)
                const int*   __restrict__ fpn_levels,   // (n,)
                const float* __restrict__ rec,          // (4,16384,12)
                float*       __restrict__ out)          // (n,1,256,256)
{
    __shared__ float lgE[17 * 64];   // even cols
    __shared__ float lgO[17 * 64];   // odd cols

    const int bx   = blockIdx.x;
    const int inst = bx >> 3;
    const int rg   = bx & 7;
    const int tid  = threadIdx.x;
    const int r0   = rg * 16;

    const float* __restrict__ wp = inst_params + (size_t)inst * NP;
    const float s0  = shifts[2 * inst];
    const float s1  = shifts[2 * inst + 1];
    const float inv = 1.0f / (float)(64 << fpn_levels[inst]);
    const float* __restrict__ rb = rec + (size_t)im_inds[inst] * HW * RECW;

    // ---- phase A: MLP over 17x128 tile (pixel p -> tile row p>>7) ----
    auto load_px = [&](int p, float* x) {
        const int t = p >> 7;
        const int c = p & 127;
        const int r = min(max(r0 - 1 + t, 0), 127);
        const int g = r * 128 + c;
        const float4* q = (const float4*)(rb + (size_t)g * RECW);
        const float4 a = q[0], b = q[1], d = q[2];
        x[0] = (s0 - a.x) * inv;
        x[1] = (s1 - a.y) * inv;
        x[2] = a.z; x[3] = a.w;
        x[4] = b.x; x[5] = b.y; x[6] = b.z; x[7] = b.w;
        x[8] = d.x; x[9] = d.y;
    };

    auto store_px = [&](int p, float v) {
        const int t = p >> 7;
        const int c = p & 127;
        const int idx = t * 64 + (c >> 1);
        if (c & 1) lgO[idx] = v; else lgE[idx] = v;
    };

    // pair-processing: 4 pair-calls cover 2048 px, tail covers 128
    #pragma unroll
    for (int u = 0; u < 4; ++u) {
        const int pA = tid + 512 * u;
        const int pB = pA + 256;
        float xa[10], xb[10];
        load_px(pA, xa);
        load_px(pB, xb);

        float ya[8], yb[8];
        #pragma unroll
        for (int o = 0; o < 8; ++o) {
            const float bia = wp[152 + o];
            float a = bia, b = bia;
            #pragma unroll
            for (int c = 0; c < 10; ++c) {
                const float w = wp[o * 10 + c];
                a = fmaf(w, xa[c], a);
                b = fmaf(w, xb[c], b);
            }
            ya[o] = fmaxf(a, 0.f);
            yb[o] = fmaxf(b, 0.f);
        }
        float za[8], zb[8];
        #pragma unroll
        for (int o = 0; o < 8; ++o) {
            const float bia = wp[160 + o];
            float a = bia, b = bia;
            #pragma unroll
            for (int c = 0; c < 8; ++c) {
                const float w = wp[80 + o * 8 + c];
                a = fmaf(w, ya[c], a);
                b = fmaf(w, yb[c], b);
            }
            za[o] = fmaxf(a, 0.f);
            zb[o] = fmaxf(b, 0.f);
        }
        float va = wp[168], vb = va;
        #pragma unroll
        for (int c = 0; c < 8; ++c) {
            const float w = wp[144 + c];
            va = fmaf(w, za[c], va);
            vb = fmaf(w, zb[c], vb);
        }
        store_px(pA, va);
        store_px(pB, vb);
    }

    if (tid < 128) {                 // tail px 2048..2175, waves 0-1 only
        const int p = 2048 + tid;
        float x[10];
        load_px(p, x);
        float y1[8];
        #pragma unroll
        for (int o = 0; o < 8; ++o) {
            float a = wp[152 + o];
            #pragma unroll
            for (int c = 0; c < 10; ++c) a = fmaf(wp[o * 10 + c], x[c], a);
            y1[o] = fmaxf(a, 0.f);
        }
        float y2[8];
        #pragma unroll
        for (int o = 0; o < 8; ++o) {
            float a = wp[160 + o];
            #pragma unroll
            for (int c = 0; c < 8; ++c) a = fmaf(wp[80 + o * 8 + c], y1[c], a);
            y2[o] = fmaxf(a, 0.f);
        }
        float v = wp[168];
        #pragma unroll
        for (int c = 0; c < 8; ++c) v = fmaf(wp[144 + c], y2[c], v);
        store_px(p, v);
    }

    __syncthreads();

    // ---- phase B: 32 output rows x 256 cols, non-temporal float4 stores ----
    float* __restrict__ op =
        out + (size_t)inst * 65536 + (size_t)(2 * r0) * 256;
    const int w = tid >> 6;
    const int l = tid & 63;
    const int parity = w & 1;        // wave-uniform row parity

    #pragma unroll
    for (int j = 0; j < 8; ++j) {
        const int p2 = (w >> 1) + 2 * j;     // 0..15
        const int yl = 2 * p2 + parity;
        nf4 res;
        if (parity) {                // odd row: fy=0, logits row p2+1
            const float* e = lgE + (p2 + 1) * 64;
            const float* o = lgO + (p2 + 1) * 64;
            const float v0 = e[l];
            const float v1 = o[l];
            const float vm = (l > 0) ? o[l - 1] : v0;
            res = (nf4){0.5f * (vm + v0), v0, 0.5f * (v0 + v1), v1};
        } else {                     // even row: fy=0.5, rows p2, p2+1
            const float* eA = lgE + p2 * 64;
            const float* oA = lgO + p2 * 64;
            const float* eB = eA + 64;
            const float* oB = oA + 64;
            const float v0A = eA[l], v1A = oA[l];
            const float v0B = eB[l], v1B = oB[l];
            const float vmA = (l > 0) ? oA[l - 1] : v0A;
            const float vmB = (l > 0) ? oB[l - 1] : v0B;
            res = (nf4){0.25f * (vmA + v0A + vmB + v0B),
                        0.5f  * (v0A + v0B),
                        0.25f * (v0A + v1A + v0B + v1B),
                        0.5f  * (v1A + v1B)};
        }
        __builtin_nontemporal_store(res, (nf4*)(op + yl * 256 + 4 * l));
    }
}

extern "C" void kernel_launch(void* const* d_in, const int* in_sizes, int n_in,
                              void* d_out, int out_size, void* d_ws, size_t ws_size,
                              hipStream_t stream) {
    (void)n_in; (void)out_size; (void)ws_size;
    const float* mask_feats  = (const float*)d_in[0];
    const float* mask_shift  = (const float*)d_in[1];
    const float* shifts      = (const float*)d_in[2];
    const float* inst_params = (const float*)d_in[3];
    const int*   im_inds     = (const int*)d_in[4];
    const int*   fpn_levels  = (const int*)d_in[5];
    float* out = (float*)d_out;
    float* rec = (float*)d_ws;   // 4*16384*12*4 B = 3.1 MB

    const int n_inst = in_sizes[2] / 2;            // shifts is (n,2)

    pack_kernel<<<dim3(4 * HW / 256), dim3(256), 0, stream>>>(
        mask_feats, mask_shift, rec);

    dmh_kernel<<<dim3(n_inst * 8), dim3(256), 0, stream>>>(
        shifts, inst_params, im_inds, fpn_levels, rec, out);
}

// Round 7
// 154.287 us; speedup vs baseline: 1.1256x; 1.1256x over previous
//
#include <hip/hip_runtime.h>

// DynamicMaskHead fused v6 (MI355X / gfx950)
// pack_kernel: (mask_shift, mask_feats) -> rec (4,16384,12) records:
//   {m0, m1, f0..f7, pad, pad} -> per-pixel input = 3 x global_load_dwordx4.
// dmh_kernel: grid = n_inst x 16 row-groups (8 logits rows -> 16 out rows),
//   6400 blocks for occupancy (25/CU vs 8-resident cap -> smooth tail).
//   9x128 logits tile (clamped halo row above) via 10->8->8->1 MLP with
//   block-uniform scalar weights, pair-processed for ILP, parity-split LDS,
//   factor-2 aligned_bilinear closed form, plain float4 stores.
//
// aligned_bilinear(factor=2), local row yl (0..15), tile rows 0..8:
//   odd  yl: copy tile row (yl+1)/2                (fy=0)
//   even yl: avg  tile rows yl/2, yl/2+1           (fy=0.5)
//   Y=0 case falls out: clamped halo makes tile row 0 == row 1.
// In X: out[4l..4l+3] from logits cols {2l-1, 2l, 2l+1} (parity-split LDS).

#define HW 16384
#define NP 169
#define RECW 12   // floats per record

__global__ __launch_bounds__(256)
void pack_kernel(const float* __restrict__ mf, const float* __restrict__ msf,
                 float* __restrict__ rec)
{
    const int g   = blockIdx.x * 256 + threadIdx.x;   // 0..65535
    const int img = g >> 14;
    const int p   = g & 16383;
    const float* fb = mf + (size_t)img * 8 * HW + p;
    const float2 ms = *(const float2*)(msf + 2 * p);
    float4* o = (float4*)(rec + (size_t)g * RECW);
    o[0] = make_float4(ms.x, ms.y, fb[0], fb[HW]);
    o[1] = make_float4(fb[2 * HW], fb[3 * HW], fb[4 * HW], fb[5 * HW]);
    o[2] = make_float4(fb[6 * HW], fb[7 * HW], 0.f, 0.f);
}

__global__ __launch_bounds__(256, 8)
void dmh_kernel(const float* __restrict__ shifts,       // (n,2)
                const float* __restrict__ inst_params,  // (n,169)
                const int*   __restrict__ im_inds,      // (n,)
                const int*   __restrict__ fpn_levels,   // (n,)
                const float* __restrict__ rec,          // (4,16384,12)
                float*       __restrict__ out)          // (n,1,256,256)
{
    __shared__ float lgE[9 * 64];    // even cols
    __shared__ float lgO[9 * 64];    // odd cols

    const int bx   = blockIdx.x;
    const int inst = bx >> 4;
    const int rg   = bx & 15;
    const int tid  = threadIdx.x;
    const int r0   = rg * 8;

    const float* __restrict__ wp = inst_params + (size_t)inst * NP;
    const float s0  = shifts[2 * inst];
    const float s1  = shifts[2 * inst + 1];
    const float inv = 1.0f / (float)(64 << fpn_levels[inst]);
    const float* __restrict__ rb = rec + (size_t)im_inds[inst] * HW * RECW;

    // ---- phase A: MLP over 9x128 tile (1152 px) ----
    auto load_px = [&](int p, float* x) {
        const int t = p >> 7;                  // tile row 0..8
        const int c = p & 127;
        const int r = min(max(r0 - 1 + t, 0), 127);
        const int g = r * 128 + c;
        const float4* q = (const float4*)(rb + (size_t)g * RECW);
        const float4 a = q[0], b = q[1], d = q[2];
        x[0] = (s0 - a.x) * inv;
        x[1] = (s1 - a.y) * inv;
        x[2] = a.z; x[3] = a.w;
        x[4] = b.x; x[5] = b.y; x[6] = b.z; x[7] = b.w;
        x[8] = d.x; x[9] = d.y;
    };

    auto store_px = [&](int p, float v) {
        const int t = p >> 7;
        const int c = p & 127;
        const int idx = t * 64 + (c >> 1);
        if (c & 1) lgO[idx] = v; else lgE[idx] = v;
    };

    // pair-processing: 2 pair-calls cover 1024 px, tail covers 128
    #pragma unroll
    for (int u = 0; u < 2; ++u) {
        const int pA = tid + 512 * u;
        const int pB = pA + 256;
        float xa[10], xb[10];
        load_px(pA, xa);
        load_px(pB, xb);

        float ya[8], yb[8];
        #pragma unroll
        for (int o = 0; o < 8; ++o) {
            const float bia = wp[152 + o];
            float a = bia, b = bia;
            #pragma unroll
            for (int c = 0; c < 10; ++c) {
                const float w = wp[o * 10 + c];
                a = fmaf(w, xa[c], a);
                b = fmaf(w, xb[c], b);
            }
            ya[o] = fmaxf(a, 0.f);
            yb[o] = fmaxf(b, 0.f);
        }
        float za[8], zb[8];
        #pragma unroll
        for (int o = 0; o < 8; ++o) {
            const float bia = wp[160 + o];
            float a = bia, b = bia;
            #pragma unroll
            for (int c = 0; c < 8; ++c) {
                const float w = wp[80 + o * 8 + c];
                a = fmaf(w, ya[c], a);
                b = fmaf(w, yb[c], b);
            }
            za[o] = fmaxf(a, 0.f);
            zb[o] = fmaxf(b, 0.f);
        }
        float va = wp[168], vb = va;
        #pragma unroll
        for (int c = 0; c < 8; ++c) {
            const float w = wp[144 + c];
            va = fmaf(w, za[c], va);
            vb = fmaf(w, zb[c], vb);
        }
        store_px(pA, va);
        store_px(pB, vb);
    }

    if (tid < 128) {                 // tail px 1024..1151, waves 0-1 only
        const int p = 1024 + tid;
        float x[10];
        load_px(p, x);
        float y1[8];
        #pragma unroll
        for (int o = 0; o < 8; ++o) {
            float a = wp[152 + o];
            #pragma unroll
            for (int c = 0; c < 10; ++c) a = fmaf(wp[o * 10 + c], x[c], a);
            y1[o] = fmaxf(a, 0.f);
        }
        float y2[8];
        #pragma unroll
        for (int o = 0; o < 8; ++o) {
            float a = wp[160 + o];
            #pragma unroll
            for (int c = 0; c < 8; ++c) a = fmaf(wp[80 + o * 8 + c], y1[c], a);
            y2[o] = fmaxf(a, 0.f);
        }
        float v = wp[168];
        #pragma unroll
        for (int c = 0; c < 8; ++c) v = fmaf(wp[144 + c], y2[c], v);
        store_px(p, v);
    }

    __syncthreads();

    // ---- phase B: 16 output rows x 256 cols, float4 stores ----
    float* __restrict__ op =
        out + (size_t)inst * 65536 + (size_t)(2 * r0) * 256;
    const int w = tid >> 6;          // wave id; parity of output row uniform
    const int l = tid & 63;

    #pragma unroll
    for (int j = 0; j < 4; ++j) {
        const int yl = w + 4 * j;    // 0..15, parity == parity of w
        float4 res;
        if (w & 1) {                 // odd row: fy=0, tile row (yl+1)/2
            const int t0 = (yl + 1) >> 1;
            const float* e = lgE + t0 * 64;
            const float* o = lgO + t0 * 64;
            const float v0 = e[l];
            const float v1 = o[l];
            const float vm = (l > 0) ? o[l - 1] : v0;
            res = make_float4(0.5f * (vm + v0), v0, 0.5f * (v0 + v1), v1);
        } else {                     // even row: fy=0.5, tile rows yl/2, yl/2+1
            const int t0 = yl >> 1;
            const float* eA = lgE + t0 * 64;
            const float* oA = lgO + t0 * 64;
            const float* eB = eA + 64;
            const float* oB = oA + 64;
            const float v0A = eA[l], v1A = oA[l];
            const float v0B = eB[l], v1B = oB[l];
            const float vmA = (l > 0) ? oA[l - 1] : v0A;
            const float vmB = (l > 0) ? oB[l - 1] : v0B;
            res = make_float4(0.25f * (vmA + v0A + vmB + v0B),
                              0.5f  * (v0A + v0B),
                              0.25f * (v0A + v1A + v0B + v1B),
                              0.5f  * (v1A + v1B));
        }
        *(float4*)(op + yl * 256 + 4 * l) = res;
    }
}

extern "C" void kernel_launch(void* const* d_in, const int* in_sizes, int n_in,
                              void* d_out, int out_size, void* d_ws, size_t ws_size,
                              hipStream_t stream) {
    (void)n_in; (void)out_size; (void)ws_size;
    const float* mask_feats  = (const float*)d_in[0];
    const float* mask_shift  = (const float*)d_in[1];
    const float* shifts      = (const float*)d_in[2];
    const float* inst_params = (const float*)d_in[3];
    const int*   im_inds     = (const int*)d_in[4];
    const int*   fpn_levels  = (const int*)d_in[5];
    float* out = (float*)d_out;
    float* rec = (float*)d_ws;   // 4*16384*12*4 B = 3.1 MB

    const int n_inst = in_sizes[2] / 2;            // shifts is (n,2)

    pack_kernel<<<dim3(4 * HW / 256), dim3(256), 0, stream>>>(
        mask_feats, mask_shift, rec);

    dmh_kernel<<<dim3(n_inst * 16), dim3(256), 0, stream>>>(
        shifts, inst_params, im_inds, fpn_levels, rec, out);
}